// Round 7
// baseline (679.339 us; speedup 1.0000x reference)
//
#include <hip/hip_runtime.h>
#include <hip/hip_cooperative_groups.h>
#include <math.h>

namespace cg = cooperative_groups;

#define TT 40          // total query tokens (sum of q_seqlens)
#define NB 16          // batch
#define HQn 16         // query heads
#define HKn 8          // kv heads
#define Gn 2           // GQA group
#define Dn 256         // head dim
#define HID 3072
#define QKV_COLS 8192  // 4096 + 2048 + 2048
#define NCHUNK 16
#define CHUNKT 128
#define MAXGRID 768

// One cooperative kernel, 6 phases, 5 grid syncs. Phase bodies identical to
// the round-6 split kernels; only shared-mem plumbing and grid-striding added.
__global__ __launch_bounds__(256, 3) void mega(
    const float* __restrict__ hs, const float* __restrict__ Wq,
    const float* __restrict__ Wk, const float* __restrict__ Wv,
    const float* __restrict__ Wo, const float* __restrict__ k_cache,
    const float* __restrict__ v_cache, const float* __restrict__ inv_freq,
    const int* __restrict__ pos_ids, const int* __restrict__ q_start,
    const int* __restrict__ q_lens, const int* __restrict__ kv_lens,
    const int* __restrict__ blk_off,
    float* __restrict__ qbuf, float* __restrict__ kbuf, float* __restrict__ vbuf,
    float* __restrict__ attn_out, float* __restrict__ part1,
    float* __restrict__ part_o, float* __restrict__ part_ml,
    float* __restrict__ part2, float* __restrict__ out) {
  cg::grid_group grd = cg::this_grid();
  __shared__ __align__(16) char smem[50240];
  const int tid = threadIdx.x;
  const int NGRID = gridDim.x;

  // ================= phase 1: QKV partial GEMM (512 virt) =================
  {
    float (*h_lds)[64] = (float (*)[64])smem;
    for (int v = blockIdx.x; v < 512; v += NGRID) {
      const int tile = v & 31;
      const int ks = v >> 5;
      const int c0 = tile << 8;
      const float* W; int ld, cw0;
      if (tile < 16)      { W = Wq; ld = 4096; cw0 = c0; }
      else if (tile < 24) { W = Wk; ld = 2048; cw0 = c0 - 4096; }
      else                { W = Wv; ld = 2048; cw0 = c0 - 6144; }
      const int kbase = ks * 192;
      const int cq = (tid & 63) << 2;
      const int r0 = (tid >> 6) * 10;
      float acc[10][4];
#pragma unroll
      for (int r = 0; r < 10; ++r) { acc[r][0]=0.f; acc[r][1]=0.f; acc[r][2]=0.f; acc[r][3]=0.f; }
      for (int kc = 0; kc < 192; kc += 64) {
        __syncthreads();
        for (int i = tid; i < 2560; i += 256) {
          int t = i >> 6, kk = i & 63;
          h_lds[t][kk] = hs[t * HID + kbase + kc + kk];
        }
        __syncthreads();
        const float* wp = W + (size_t)(kbase + kc) * ld + cw0 + cq;
#pragma unroll 8
        for (int kk = 0; kk < 64; ++kk) {
          float4 w4 = *reinterpret_cast<const float4*>(wp + (size_t)kk * ld);
#pragma unroll
          for (int r = 0; r < 10; ++r) {
            float h = h_lds[r0 + r][kk];
            acc[r][0] = fmaf(h, w4.x, acc[r][0]);
            acc[r][1] = fmaf(h, w4.y, acc[r][1]);
            acc[r][2] = fmaf(h, w4.z, acc[r][2]);
            acc[r][3] = fmaf(h, w4.w, acc[r][3]);
          }
        }
      }
#pragma unroll
      for (int r = 0; r < 10; ++r) {
        int t = r0 + r;
        float4 vv = make_float4(acc[r][0], acc[r][1], acc[r][2], acc[r][3]);
        *reinterpret_cast<float4*>(&part1[(size_t)(ks * TT + t) * QKV_COLS + c0 + cq]) = vv;
      }
      __syncthreads();
    }
  }
  grd.sync();

  // ================= phase 2: k-split reduce + RoPE (1280 virt) =================
  {
    float* sl = (float*)smem;
    for (int v = blockIdx.x; v < 1280; v += NGRID) {
      const int t = v >> 5;
      const int tile = v & 31;
      const int c = (tile << 8) + tid;
      float s = 0.f;
#pragma unroll
      for (int ks = 0; ks < 16; ++ks) s += part1[(size_t)(ks * TT + t) * QKV_COLS + c];
      __syncthreads();
      sl[tid] = s;
      __syncthreads();
      if (tile < 24) {
        const int d = tid;
        const int d2 = d & 127;
        float fr = (float)pos_ids[t] * inv_freq[d2];
        float cs = cosf(fr), sn = sinf(fr);
        float val = (d < 128) ? (sl[d] * cs - sl[d + 128] * sn)
                              : (sl[d] * cs + sl[d - 128] * sn);
        if (tile < 16) qbuf[t * 4096 + (tile << 8) + d] = val * 0.0625f;
        else           kbuf[t * 2048 + ((tile - 16) << 8) + d] = val;
      } else {
        vbuf[t * 2048 + ((tile - 24) << 8) + tid] = s;
      }
      __syncthreads();
    }
  }
  grd.sync();

  // ================= phase 3: flash-decode attention partials (2048 virt) =================
  {
    float (*q_lds)[256] = (float (*)[256])smem;                    //  8192 B
    float (*S2)[8]      = (float (*)[8])(smem + 8192);             //  8192 B ([256][8], h*128+row)
    float (*red)[8]     = (float (*)[8])(smem + 16384);            //  1024 B
    float* Mg           = (float*)(smem + 17408);                  //    32 B
    float (*obuf)[256]  = (float (*)[256])(smem + 17472);          // 32768 B ([32][256] = [w*8+q][d])
    const int w = tid >> 6;
    const int lane = tid & 63;
    const int tp = lane & 7;
    const int qd = lane >> 3;

    for (int v = blockIdx.x; v < 2048; v += NGRID) {
      const int chunk = v & 15;
      const int hk = (v >> 4) & 7;
      const int b = v >> 7;
      const int kv_len = kv_lens[b];
      const int cs0 = chunk * CHUNKT;
      if (cs0 < kv_len) {
        const int q_cnt = q_lens[b];
        const int hist = kv_len - q_cnt;
        const int q0 = q_start[b];
        const int nq = q_cnt * 2;

        const int bi = (b << 5) + (cs0 >> 6);
        const int blk0v = blk_off[bi];
        const int blk1v = blk_off[bi + 1];
        const float* kb0  = k_cache + ((size_t)blk0v << 17) + ((size_t)hk << 8);
        const float* kb1  = k_cache + ((size_t)blk1v << 17) + ((size_t)hk << 8);
        const float* vb0  = v_cache + ((size_t)blk0v << 17) + ((size_t)hk << 8);
        const float* vb1  = v_cache + ((size_t)blk1v << 17) + ((size_t)hk << 8);
        const float* knew = kbuf + ((size_t)q0 << 11) + ((size_t)hk << 8);
        const float* vnew = vbuf + ((size_t)q0 << 11) + ((size_t)hk << 8);

        auto rowK = [&](int s) -> const float* {
          if (s < hist) {
            const float* base = (s & 64) ? kb1 : kb0;
            return base + ((size_t)(s & 63) << 11);
          }
          return knew + ((size_t)(s - hist) << 11);
        };
        auto rowV = [&](int s) -> const float* {
          if (s < hist) {
            const float* base = (s & 64) ? vb1 : vb0;
            return base + ((size_t)(s & 63) << 11);
          }
          return vnew + ((size_t)(s - hist) << 11);
        };

        __syncthreads();   // protect smem reuse across virt iterations
        // stage Q (scale folded)
        for (int i = tid; i < 2048; i += 256) {
          int qv = i >> 8, d = i & 255;
          int qtok = min(qv >> 1, q_cnt - 1);
          q_lds[qv][d] = qbuf[(size_t)(q0 + qtok) * 4096 + (hk * Gn + (qv & 1)) * 256 + d];
        }
        __syncthreads();

        const int sBeg = cs0 + (w << 5);

        // ---- score phase ----
        const float* kr[4];
#pragma unroll
        for (int tt = 0; tt < 4; ++tt) {
          int s = sBeg + (tp << 2) + tt;
          int sc = s < kv_len ? s : kv_len - 1;
          kr[tt] = rowK(sc) + (qd << 2);
        }
        float acc[4][8];
#pragma unroll
        for (int tt = 0; tt < 4; ++tt)
#pragma unroll
          for (int qv = 0; qv < 8; ++qv) acc[tt][qv] = 0.f;
#pragma unroll
        for (int c = 0; c < 8; ++c) {
          float4 kf[4];
#pragma unroll
          for (int tt = 0; tt < 4; ++tt)
            kf[tt] = *reinterpret_cast<const float4*>(kr[tt] + (c << 5));
#pragma unroll
          for (int qv = 0; qv < 8; ++qv) {
            float4 qf = *reinterpret_cast<const float4*>(&q_lds[qv][(qd << 2) + (c << 5)]);
#pragma unroll
            for (int tt = 0; tt < 4; ++tt) {
              acc[tt][qv] = fmaf(qf.x, kf[tt].x, acc[tt][qv]);
              acc[tt][qv] = fmaf(qf.y, kf[tt].y, acc[tt][qv]);
              acc[tt][qv] = fmaf(qf.z, kf[tt].z, acc[tt][qv]);
              acc[tt][qv] = fmaf(qf.w, kf[tt].w, acc[tt][qv]);
            }
          }
        }
#pragma unroll
        for (int tt = 0; tt < 4; ++tt)
#pragma unroll
          for (int qv = 0; qv < 8; ++qv) {
            float val = acc[tt][qv];
            val += __shfl_xor(val, 8);
            val += __shfl_xor(val, 16);
            acc[tt][qv] = val;
          }
        if ((lane & 24) == 0) {
          const int h = lane >> 5;
#pragma unroll
          for (int tt = 0; tt < 4; ++tt) {
            int srel = (w << 5) + (tp << 2) + tt;
            *reinterpret_cast<float4*>(&S2[(h << 7) + srel][0]) =
                make_float4(acc[tt][0], acc[tt][1], acc[tt][2], acc[tt][3]);
            *reinterpret_cast<float4*>(&S2[(h << 7) + srel][4]) =
                make_float4(acc[tt][4], acc[tt][5], acc[tt][6], acc[tt][7]);
          }
        }
        __syncthreads();

        // ---- softmax ----
        const int qv2 = tid & 7;
        const int grp = tid >> 3;
        float sv[4];
        {
          float mloc = -1e30f;
#pragma unroll
          for (int t = 0; t < 4; ++t) {
            int sl2 = (grp << 2) + t;
            float val = S2[sl2][qv2] + S2[128 + sl2][qv2];
            bool valid = (qv2 < nq) && ((cs0 + sl2 - hist) <= (qv2 >> 1));
            val = valid ? val : -1e30f;
            sv[t] = val;
            mloc = fmaxf(mloc, val);
          }
          red[grp][qv2] = mloc;
        }
        __syncthreads();
        if (tid < 8) {
          float M = -1e30f;
#pragma unroll
          for (int i = 0; i < 32; ++i) M = fmaxf(M, red[i][tid]);
          Mg[tid] = M;
        }
        __syncthreads();
        {
          float M = Mg[qv2];
          float lloc = 0.f;
#pragma unroll
          for (int t = 0; t < 4; ++t) {
            float p = __expf(sv[t] - M);
            S2[(grp << 2) + t][qv2] = p;
            lloc += p;
          }
          red[grp][qv2] = lloc;
        }
        __syncthreads();
        if (tid < 8) {
          float L = 0.f;
#pragma unroll
          for (int i = 0; i < 32; ++i) L += red[i][tid];
          int pidx = (((b * HKn + hk) * NCHUNK + chunk) << 3) + tid;
          part_ml[pidx * 2] = Mg[tid];
          part_ml[pidx * 2 + 1] = L;
        }

        // ---- PV phase ----
        float4 pacc[8];
#pragma unroll
        for (int q = 0; q < 8; ++q) pacc[q] = make_float4(0.f, 0.f, 0.f, 0.f);
        const int d4 = lane << 2;
#pragma unroll 4
        for (int t = 0; t < 32; ++t) {
          int s = sBeg + t;
          int sc = s < kv_len ? s : kv_len - 1;
          float4 vf = *reinterpret_cast<const float4*>(rowV(sc) + d4);
          int srel = (w << 5) + t;
          float4 p0 = *reinterpret_cast<const float4*>(&S2[srel][0]);
          float4 p1 = *reinterpret_cast<const float4*>(&S2[srel][4]);
          float pr[8] = {p0.x, p0.y, p0.z, p0.w, p1.x, p1.y, p1.z, p1.w};
#pragma unroll
          for (int q = 0; q < 8; ++q) {
            pacc[q].x = fmaf(pr[q], vf.x, pacc[q].x);
            pacc[q].y = fmaf(pr[q], vf.y, pacc[q].y);
            pacc[q].z = fmaf(pr[q], vf.z, pacc[q].z);
            pacc[q].w = fmaf(pr[q], vf.w, pacc[q].w);
          }
        }
#pragma unroll
        for (int q = 0; q < 8; ++q)
          *reinterpret_cast<float4*>(&obuf[w * 8 + q][d4]) = pacc[q];
        __syncthreads();

        for (int q = 0; q < nq; ++q) {
          float o = obuf[q][tid] + obuf[8 + q][tid] + obuf[16 + q][tid] + obuf[24 + q][tid];
          int pidx = (((b * HKn + hk) * NCHUNK + chunk) << 3) + q;
          part_o[(size_t)pidx * 256 + tid] = o;
        }
        __syncthreads();
      }
    }
  }
  grd.sync();

  // ================= phase 4: combine chunk partials (1024 wave-units) =================
  {
    const int w = tid >> 6;
    const int lane = tid & 63;
    for (int u = blockIdx.x * 4 + w; u < 1024; u += NGRID * 4) {
      const int h = u & 15;
      const int qtok = (u >> 4) & 3;
      const int b = u >> 6;
      const int q_cnt = q_lens[b];
      if (qtok < q_cnt) {
        const int kv_len = kv_lens[b];
        const int nparts = (kv_len + CHUNKT - 1) >> 7;
        const int qv = qtok * 2 + (h & 1);
        const int hk = h >> 1;
        const int pbase = ((b * HKn + hk) * NCHUNK) << 3;
        float2 mls[16];
#pragma unroll
        for (int i = 0; i < 16; ++i)
          if (i < nparts)
            mls[i] = *reinterpret_cast<const float2*>(&part_ml[(size_t)(pbase + (i << 3) + qv) * 2]);
        float M = -1e30f;
#pragma unroll
        for (int i = 0; i < 16; ++i)
          if (i < nparts) M = fmaxf(M, mls[i].x);
        float4 o = make_float4(0.f, 0.f, 0.f, 0.f);
        float L = 0.f;
#pragma unroll
        for (int i = 0; i < 16; ++i)
          if (i < nparts) {
            float corr = __expf(mls[i].x - M);
            L += corr * mls[i].y;
            float4 pv = *reinterpret_cast<const float4*>(
                &part_o[(size_t)(pbase + (i << 3) + qv) * 256 + (lane << 2)]);
            o.x = fmaf(corr, pv.x, o.x);
            o.y = fmaf(corr, pv.y, o.y);
            o.z = fmaf(corr, pv.z, o.z);
            o.w = fmaf(corr, pv.w, o.w);
          }
        float inv = 1.0f / L;
        int tr = q_start[b] + qtok;
        float4 res = make_float4(o.x * inv, o.y * inv, o.z * inv, o.w * inv);
        *reinterpret_cast<float4*>(&attn_out[((size_t)tr * HQn + h) * 256 + (lane << 2)]) = res;
      }
    }
  }
  grd.sync();

  // ================= phase 5: output GEMM partial (384 virt) =================
  {
    float (*h_lds)[64] = (float (*)[64])smem;
    for (int v = blockIdx.x; v < 384; v += NGRID) {
      const int tile = v % 12;
      const int ks = v / 12;
      const int c0 = tile << 8;
      const int kbase = ks << 7;
      const int cq = (tid & 63) << 2;
      const int r0 = (tid >> 6) * 10;
      float acc[10][4];
#pragma unroll
      for (int r = 0; r < 10; ++r) { acc[r][0]=0.f; acc[r][1]=0.f; acc[r][2]=0.f; acc[r][3]=0.f; }
      for (int kc = 0; kc < 128; kc += 64) {
        __syncthreads();
        for (int i = tid; i < 2560; i += 256) {
          int t = i >> 6, kk = i & 63;
          h_lds[t][kk] = attn_out[(size_t)t * 4096 + kbase + kc + kk];
        }
        __syncthreads();
        const float* wp = Wo + (size_t)(kbase + kc) * 3072 + c0 + cq;
#pragma unroll 8
        for (int kk = 0; kk < 64; ++kk) {
          float4 w4 = *reinterpret_cast<const float4*>(wp + (size_t)kk * 3072);
#pragma unroll
          for (int r = 0; r < 10; ++r) {
            float h = h_lds[r0 + r][kk];
            acc[r][0] = fmaf(h, w4.x, acc[r][0]);
            acc[r][1] = fmaf(h, w4.y, acc[r][1]);
            acc[r][2] = fmaf(h, w4.z, acc[r][2]);
            acc[r][3] = fmaf(h, w4.w, acc[r][3]);
          }
        }
      }
#pragma unroll
      for (int r = 0; r < 10; ++r) {
        int t = r0 + r;
        float4 vv = make_float4(acc[r][0], acc[r][1], acc[r][2], acc[r][3]);
        *reinterpret_cast<float4*>(&part2[(size_t)(ks * TT + t) * 3072 + c0 + cq]) = vv;
      }
      __syncthreads();
    }
  }
  grd.sync();

  // ================= phase 6: final k-split reduce (122880 elems) =================
  for (int idx = blockIdx.x * 256 + tid; idx < 122880; idx += NGRID * 256) {
    float s = 0.f;
#pragma unroll
    for (int ks = 0; ks < 32; ++ks) s += part2[(size_t)ks * 122880 + idx];
    out[idx] = s;
  }
}

extern "C" void kernel_launch(void* const* d_in, const int* in_sizes, int n_in,
                              void* d_out, int out_size, void* d_ws, size_t ws_size,
                              hipStream_t stream) {
  const float* hs       = (const float*)d_in[0];
  const float* Wq       = (const float*)d_in[1];
  const float* Wk       = (const float*)d_in[2];
  const float* Wv       = (const float*)d_in[3];
  const float* Wo       = (const float*)d_in[4];
  const float* k_cache  = (const float*)d_in[5];
  const float* v_cache  = (const float*)d_in[6];
  const float* inv_freq = (const float*)d_in[7];
  const int*   pos_ids  = (const int*)d_in[8];
  const int*   q_start  = (const int*)d_in[9];
  const int*   q_lens   = (const int*)d_in[10];
  const int*   kv_lens  = (const int*)d_in[11];
  const int*   blk_off  = (const int*)d_in[12];

  float* ws = (float*)d_ws;
  float* qbuf     = ws;                 // 40*4096
  float* kbuf     = ws + 163840;        // 40*2048
  float* vbuf     = ws + 245760;        // 40*2048
  float* attn_out = ws + 327680;        // 40*4096
  float* big      = ws + 491520;        // reused region
  float* part1    = big;                // 16*40*8192
  float* part_o   = big;                // 16384*256
  float* part_ml  = big + 4194304;      // 16384*2
  float* part2    = big;                // 32*40*3072
  float* out      = (float*)d_out;

  int maxb = 0;
  hipOccupancyMaxActiveBlocksPerMultiprocessor(&maxb, (const void*)mega, 256, 0);
  int grid = maxb * 256;
  if (grid > MAXGRID) grid = MAXGRID;
  if (grid < 1) grid = 1;

  void* args[] = {
    (void*)&hs, (void*)&Wq, (void*)&Wk, (void*)&Wv, (void*)&Wo,
    (void*)&k_cache, (void*)&v_cache, (void*)&inv_freq, (void*)&pos_ids,
    (void*)&q_start, (void*)&q_lens, (void*)&kv_lens, (void*)&blk_off,
    (void*)&qbuf, (void*)&kbuf, (void*)&vbuf, (void*)&attn_out,
    (void*)&part1, (void*)&part_o, (void*)&part_ml, (void*)&part2, (void*)&out
  };
  hipLaunchCooperativeKernel((void*)mega, dim3(grid), dim3(256), args, 0, stream);
}

// Round 8
// 365.547 us; speedup vs baseline: 1.8584x; 1.8584x over previous
//
#include <hip/hip_runtime.h>
#include <math.h>

#define TT 40          // total query tokens (sum of q_seqlens)
#define NB 16          // batch
#define HQn 16         // query heads
#define HKn 8          // kv heads
#define Gn 2           // GQA group
#define Dn 256         // head dim
#define HID 3072
#define QKV_COLS 8192  // 4096 + 2048 + 2048
#define NCHUNK 16
#define CHUNKT 128

// ---------------- K1: QKV partial GEMM ----------------
// grid 512 = 32 col-tiles(256) * 16 k-splits(192), block 256
// thread: 8 cols x 5 rows; h via ds_read_b128 (LDS instr/FMA ratio 1:32)
__global__ __launch_bounds__(256, 4) void k1_qkv_gemm(
    const float* __restrict__ hs, const float* __restrict__ Wq,
    const float* __restrict__ Wk, const float* __restrict__ Wv,
    float* __restrict__ part1) {
  const int tile = blockIdx.x & 31;
  const int ks = blockIdx.x >> 5;
  const int c0 = tile << 8;
  const float* W; int ld, cw0;
  if (tile < 16)      { W = Wq; ld = 4096; cw0 = c0; }
  else if (tile < 24) { W = Wk; ld = 2048; cw0 = c0 - 4096; }
  else                { W = Wv; ld = 2048; cw0 = c0 - 6144; }
  const int kbase = ks * 192;
  const int cq = (threadIdx.x & 31) << 3;   // 8 cols
  const int r0 = (threadIdx.x >> 5) * 5;    // 5 rows
  __shared__ float h_lds[40][64];
  float acc[5][8];
#pragma unroll
  for (int r = 0; r < 5; ++r)
#pragma unroll
    for (int c = 0; c < 8; ++c) acc[r][c] = 0.f;
  for (int kc = 0; kc < 192; kc += 64) {
    __syncthreads();
    for (int i = threadIdx.x; i < 2560; i += 256) {
      int t = i >> 6, kk = i & 63;
      h_lds[t][kk] = hs[t * HID + kbase + kc + kk];
    }
    __syncthreads();
    const float* wp = W + (size_t)(kbase + kc) * ld + cw0 + cq;
#pragma unroll 2
    for (int k4 = 0; k4 < 16; ++k4) {
      float4 h4[5];
#pragma unroll
      for (int r = 0; r < 5; ++r)
        h4[r] = *reinterpret_cast<const float4*>(&h_lds[r0 + r][k4 << 2]);
#pragma unroll
      for (int j = 0; j < 4; ++j) {
        const float* wr = wp + (size_t)((k4 << 2) + j) * ld;
        float4 wa = *reinterpret_cast<const float4*>(wr);
        float4 wb = *reinterpret_cast<const float4*>(wr + 4);
#pragma unroll
        for (int r = 0; r < 5; ++r) {
          float hv = (j == 0) ? h4[r].x : (j == 1) ? h4[r].y : (j == 2) ? h4[r].z : h4[r].w;
          acc[r][0] = fmaf(hv, wa.x, acc[r][0]);
          acc[r][1] = fmaf(hv, wa.y, acc[r][1]);
          acc[r][2] = fmaf(hv, wa.z, acc[r][2]);
          acc[r][3] = fmaf(hv, wa.w, acc[r][3]);
          acc[r][4] = fmaf(hv, wb.x, acc[r][4]);
          acc[r][5] = fmaf(hv, wb.y, acc[r][5]);
          acc[r][6] = fmaf(hv, wb.z, acc[r][6]);
          acc[r][7] = fmaf(hv, wb.w, acc[r][7]);
        }
      }
    }
  }
#pragma unroll
  for (int r = 0; r < 5; ++r) {
    int t = r0 + r;
    float* dst = &part1[(size_t)(ks * TT + t) * QKV_COLS + c0 + cq];
    *reinterpret_cast<float4*>(dst) = make_float4(acc[r][0], acc[r][1], acc[r][2], acc[r][3]);
    *reinterpret_cast<float4*>(dst + 4) = make_float4(acc[r][4], acc[r][5], acc[r][6], acc[r][7]);
  }
}

// ---------------- K2: k-split reduce + RoPE ----------------
// grid 1280 = 40 tokens * 32 tiles, block 256
__global__ __launch_bounds__(256) void k2_reduce_rope(
    const float* __restrict__ part1, const float* __restrict__ inv_freq,
    const int* __restrict__ pos_ids,
    float* __restrict__ qbuf, float* __restrict__ kbuf, float* __restrict__ vbuf) {
  const int t = blockIdx.x >> 5;
  const int tile = blockIdx.x & 31;
  const int c = (tile << 8) + threadIdx.x;
  float s = 0.f;
#pragma unroll
  for (int ks = 0; ks < 16; ++ks) s += part1[(size_t)(ks * TT + t) * QKV_COLS + c];
  __shared__ float sl[256];
  sl[threadIdx.x] = s;
  __syncthreads();
  if (tile < 24) {   // q or k head: apply neox RoPE
    const int d = threadIdx.x;
    const int d2 = d & 127;
    float fr = (float)pos_ids[t] * inv_freq[d2];
    float cs = cosf(fr), sn = sinf(fr);
    float v = (d < 128) ? (sl[d] * cs - sl[d + 128] * sn)
                        : (sl[d] * cs + sl[d - 128] * sn);
    if (tile < 16) qbuf[t * 4096 + (tile << 8) + d] = v * 0.0625f;  // fold 1/sqrt(D)
    else           kbuf[t * 2048 + ((tile - 16) << 8) + d] = v;
  } else {
    vbuf[t * 2048 + ((tile - 24) << 8) + threadIdx.x] = s;
  }
}

// ---------------- K3: flash-decode attention partials (v8) ----------------
// score: token-split waves (v6 layout). PV: qv-split waves, no obuf.
// LDS 17.4 KB -> 24 waves/CU. grid 2048 = b(16)*hk(8)*chunk(16), block 256.
__global__ __launch_bounds__(256, 6) void k3_attn_partial(
    const float* __restrict__ qbuf, const float* __restrict__ kbuf,
    const float* __restrict__ vbuf, const float* __restrict__ k_cache,
    const float* __restrict__ v_cache, const int* __restrict__ blk_off,
    const int* __restrict__ q_start, const int* __restrict__ q_lens,
    const int* __restrict__ kv_lens,
    float* __restrict__ part_o, float* __restrict__ part_ml) {
  const int chunk = blockIdx.x & 15;
  const int hk = (blockIdx.x >> 4) & 7;
  const int b = blockIdx.x >> 7;
  const int kv_len = kv_lens[b];
  const int cs0 = chunk * CHUNKT;
  if (cs0 >= kv_len) return;
  const int q_cnt = q_lens[b];
  const int hist = kv_len - q_cnt;
  const int q0 = q_start[b];
  const int nq = q_cnt * 2;

  __shared__ float q_lds[8][256];     // 8 KB
  __shared__ float S2[2][128][8];     // 8 KB: two half-sums -> p values
  __shared__ float red[32][8];        // 1 KB
  __shared__ float Mg[8];

  const int tid = threadIdx.x;
  const int w = tid >> 6;
  const int lane = tid & 63;
  const int tp = lane & 7;    // token quad within wave's 32 (score phase)
  const int qd = lane >> 3;   // interleaved 4-float dim slice (score phase)

  // chunk spans exactly 2 cache blocks: preload both -> pure-arith addressing
  const int bi = (b << 5) + (cs0 >> 6);
  const int blk0v = blk_off[bi];
  const int blk1v = blk_off[bi + 1];
  const float* kb0  = k_cache + ((size_t)blk0v << 17) + ((size_t)hk << 8);
  const float* kb1  = k_cache + ((size_t)blk1v << 17) + ((size_t)hk << 8);
  const float* vb0  = v_cache + ((size_t)blk0v << 17) + ((size_t)hk << 8);
  const float* vb1  = v_cache + ((size_t)blk1v << 17) + ((size_t)hk << 8);
  const float* knew = kbuf + ((size_t)q0 << 11) + ((size_t)hk << 8);
  const float* vnew = vbuf + ((size_t)q0 << 11) + ((size_t)hk << 8);

  auto rowK = [&](int s) -> const float* {
    if (s < hist) {
      const float* base = (s & 64) ? kb1 : kb0;
      return base + ((size_t)(s & 63) << 11);
    }
    return knew + ((size_t)(s - hist) << 11);
  };

  // stage Q (scale already folded): 8 qv rows x 256
  for (int i = tid; i < 2048; i += 256) {
    int qv = i >> 8, d = i & 255;
    int qtok = min(qv >> 1, q_cnt - 1);
    q_lds[qv][d] = qbuf[(size_t)(q0 + qtok) * 4096 + (hk * Gn + (qv & 1)) * 256 + d];
  }
  __syncthreads();

  const int sBeg = cs0 + (w << 5);

  // ---- score phase: lane owns 4 tokens x 32 dims (stride-32 interleave) ----
  const float* kr[4];
#pragma unroll
  for (int tt = 0; tt < 4; ++tt) {
    int s = sBeg + (tp << 2) + tt;
    int sc = s < kv_len ? s : kv_len - 1;   // clamp; masked in softmax
    kr[tt] = rowK(sc) + (qd << 2);
  }
  float acc[4][8];
#pragma unroll
  for (int tt = 0; tt < 4; ++tt)
#pragma unroll
    for (int qv = 0; qv < 8; ++qv) acc[tt][qv] = 0.f;

#pragma unroll
  for (int c = 0; c < 8; ++c) {
    float4 kf[4];
#pragma unroll
    for (int tt = 0; tt < 4; ++tt)
      kf[tt] = *reinterpret_cast<const float4*>(kr[tt] + (c << 5));
#pragma unroll
    for (int qv = 0; qv < 8; ++qv) {
      float4 qf = *reinterpret_cast<const float4*>(&q_lds[qv][(qd << 2) + (c << 5)]);
#pragma unroll
      for (int tt = 0; tt < 4; ++tt) {
        acc[tt][qv] = fmaf(qf.x, kf[tt].x, acc[tt][qv]);
        acc[tt][qv] = fmaf(qf.y, kf[tt].y, acc[tt][qv]);
        acc[tt][qv] = fmaf(qf.z, kf[tt].z, acc[tt][qv]);
        acc[tt][qv] = fmaf(qf.w, kf[tt].w, acc[tt][qv]);
      }
    }
  }
#pragma unroll
  for (int tt = 0; tt < 4; ++tt)
#pragma unroll
    for (int qv = 0; qv < 8; ++qv) {
      float v = acc[tt][qv];
      v += __shfl_xor(v, 8);
      v += __shfl_xor(v, 16);
      acc[tt][qv] = v;
    }
  if ((lane & 24) == 0) {
    const int h = lane >> 5;
#pragma unroll
    for (int tt = 0; tt < 4; ++tt) {
      int srel = (w << 5) + (tp << 2) + tt;
      *reinterpret_cast<float4*>(&S2[h][srel][0]) =
          make_float4(acc[tt][0], acc[tt][1], acc[tt][2], acc[tt][3]);
      *reinterpret_cast<float4*>(&S2[h][srel][4]) =
          make_float4(acc[tt][4], acc[tt][5], acc[tt][6], acc[tt][7]);
    }
  }
  __syncthreads();

  // ---- softmax over the whole chunk. thread: qv2 = tid&7, grp = tid>>3 ----
  const int qv2 = tid & 7;
  const int grp = tid >> 3;
  float sv[4];
  {
    float mloc = -1e30f;
#pragma unroll
    for (int t = 0; t < 4; ++t) {
      int sl = (grp << 2) + t;
      float v = S2[0][sl][qv2] + S2[1][sl][qv2];
      bool valid = (qv2 < nq) && ((cs0 + sl - hist) <= (qv2 >> 1));
      v = valid ? v : -1e30f;
      sv[t] = v;
      mloc = fmaxf(mloc, v);
    }
    red[grp][qv2] = mloc;
  }
  __syncthreads();
  if (tid < 8) {
    float M = -1e30f;
#pragma unroll
    for (int i = 0; i < 32; ++i) M = fmaxf(M, red[i][tid]);
    Mg[tid] = M;
  }
  __syncthreads();
  {
    float M = Mg[qv2];
    float lloc = 0.f;
#pragma unroll
    for (int t = 0; t < 4; ++t) {
      float p = __expf(sv[t] - M);
      S2[0][(grp << 2) + t][qv2] = p;
      lloc += p;
    }
    red[grp][qv2] = lloc;
  }
  __syncthreads();
  if (tid < 8) {
    float L = 0.f;
#pragma unroll
    for (int i = 0; i < 32; ++i) L += red[i][tid];
    int pidx = (((b * HKn + hk) * NCHUNK + chunk) << 3) + tid;
    part_ml[pidx * 2] = Mg[tid];
    part_ml[pidx * 2 + 1] = L;
  }

  // ---- PV phase: wave w owns qv pair (2w, 2w+1) over ALL chunk tokens ----
  // p == 0 for masked/tail tokens of valid qv; invalid qv never written out.
  const int qp = w << 1;
  const int d4 = lane << 2;
  float4 a0 = make_float4(0.f, 0.f, 0.f, 0.f);
  float4 a1 = make_float4(0.f, 0.f, 0.f, 0.f);
  const int lim = min(cs0 + CHUNKT, kv_len);

#define PV_STEP(VROW, SREL)                                          \
  {                                                                  \
    float4 vf = *reinterpret_cast<const float4*>(VROW);              \
    float2 pp = *reinterpret_cast<const float2*>(&S2[0][SREL][qp]);  \
    a0.x = fmaf(pp.x, vf.x, a0.x); a0.y = fmaf(pp.x, vf.y, a0.y);    \
    a0.z = fmaf(pp.x, vf.z, a0.z); a0.w = fmaf(pp.x, vf.w, a0.w);    \
    a1.x = fmaf(pp.y, vf.x, a1.x); a1.y = fmaf(pp.y, vf.y, a1.y);    \
    a1.z = fmaf(pp.y, vf.z, a1.z); a1.w = fmaf(pp.y, vf.w, a1.w);    \
  }

  {
    // region A: cache block 0 (tokens [cs0, cs0+64) ∩ [.., hist) ∩ [.., lim))
    int eA = min(min(cs0 + 64, hist), lim);
#pragma unroll 4
    for (int s = cs0; s < eA; ++s)
      PV_STEP(vb0 + ((size_t)(s & 63) << 11) + d4, s - cs0);
    // region B: cache block 1
    int eB = min(min(cs0 + 128, hist), lim);
#pragma unroll 4
    for (int s = cs0 + 64; s < eB; ++s)
      PV_STEP(vb1 + ((size_t)(s & 63) << 11) + d4, s - cs0);
    // region C: new tokens
    int bC = max(cs0, hist);
#pragma unroll
    for (int s = bC; s < lim; ++s)
      PV_STEP(vnew + ((size_t)(s - hist) << 11) + d4, s - cs0);
  }
#undef PV_STEP

  if (qp < nq) {
    int pidxb = (((b * HKn + hk) * NCHUNK + chunk) << 3) + qp;
    *reinterpret_cast<float4*>(&part_o[(size_t)pidxb * 256 + d4]) = a0;
    *reinterpret_cast<float4*>(&part_o[(size_t)(pidxb + 1) * 256 + d4]) = a1;
  }
}

// ---------------- K4: combine chunk partials ----------------
// grid 1024 = b(16)*qtok(4)*h(16), block 64
__global__ __launch_bounds__(64) void k4_attn_reduce(
    const float* __restrict__ part_o, const float* __restrict__ part_ml,
    const int* __restrict__ q_start, const int* __restrict__ q_lens,
    const int* __restrict__ kv_lens, float* __restrict__ attn_out) {
  const int h = blockIdx.x & 15;
  const int qtok = (blockIdx.x >> 4) & 3;
  const int b = blockIdx.x >> 6;
  const int q_cnt = q_lens[b];
  if (qtok >= q_cnt) return;
  const int kv_len = kv_lens[b];
  const int nparts = (kv_len + CHUNKT - 1) >> 7;
  const int qv = qtok * 2 + (h & 1);
  const int hk = h >> 1;
  const int lane = threadIdx.x;
  const int pbase = ((b * HKn + hk) * NCHUNK) << 3;
  float2 mls[16];
#pragma unroll
  for (int i = 0; i < 16; ++i)
    if (i < nparts)
      mls[i] = *reinterpret_cast<const float2*>(&part_ml[(size_t)(pbase + (i << 3) + qv) * 2]);
  float M = -1e30f;
#pragma unroll
  for (int i = 0; i < 16; ++i)
    if (i < nparts) M = fmaxf(M, mls[i].x);
  float4 o = make_float4(0.f, 0.f, 0.f, 0.f);
  float L = 0.f;
#pragma unroll
  for (int i = 0; i < 16; ++i)
    if (i < nparts) {
      float corr = __expf(mls[i].x - M);
      L += corr * mls[i].y;
      float4 pv = *reinterpret_cast<const float4*>(
          &part_o[(size_t)(pbase + (i << 3) + qv) * 256 + (lane << 2)]);
      o.x = fmaf(corr, pv.x, o.x);
      o.y = fmaf(corr, pv.y, o.y);
      o.z = fmaf(corr, pv.z, o.z);
      o.w = fmaf(corr, pv.w, o.w);
    }
  float inv = 1.0f / L;
  int tr = q_start[b] + qtok;
  float4 res = make_float4(o.x * inv, o.y * inv, o.z * inv, o.w * inv);
  *reinterpret_cast<float4*>(&attn_out[((size_t)tr * HQn + h) * 256 + (lane << 2)]) = res;
}

// ---------------- K5: output GEMM partial (attn @ Wo) ----------------
// grid 384 = 12 col-tiles(256) * 32 k-splits(128), block 256
__global__ __launch_bounds__(256, 4) void k5_out_gemm(
    const float* __restrict__ ain, const float* __restrict__ Wo,
    float* __restrict__ part2) {
  const int tile = blockIdx.x % 12;
  const int ks = blockIdx.x / 12;
  const int c0 = tile << 8;
  const int kbase = ks << 7;
  const int cq = (threadIdx.x & 31) << 3;   // 8 cols
  const int r0 = (threadIdx.x >> 5) * 5;    // 5 rows
  __shared__ float h_lds[40][64];
  float acc[5][8];
#pragma unroll
  for (int r = 0; r < 5; ++r)
#pragma unroll
    for (int c = 0; c < 8; ++c) acc[r][c] = 0.f;
  for (int kc = 0; kc < 128; kc += 64) {
    __syncthreads();
    for (int i = threadIdx.x; i < 2560; i += 256) {
      int t = i >> 6, kk = i & 63;
      h_lds[t][kk] = ain[(size_t)t * 4096 + kbase + kc + kk];
    }
    __syncthreads();
    const float* wp = Wo + (size_t)(kbase + kc) * 3072 + c0 + cq;
#pragma unroll 2
    for (int k4 = 0; k4 < 16; ++k4) {
      float4 h4[5];
#pragma unroll
      for (int r = 0; r < 5; ++r)
        h4[r] = *reinterpret_cast<const float4*>(&h_lds[r0 + r][k4 << 2]);
#pragma unroll
      for (int j = 0; j < 4; ++j) {
        const float* wr = wp + (size_t)((k4 << 2) + j) * 3072;
        float4 wa = *reinterpret_cast<const float4*>(wr);
        float4 wb = *reinterpret_cast<const float4*>(wr + 4);
#pragma unroll
        for (int r = 0; r < 5; ++r) {
          float hv = (j == 0) ? h4[r].x : (j == 1) ? h4[r].y : (j == 2) ? h4[r].z : h4[r].w;
          acc[r][0] = fmaf(hv, wa.x, acc[r][0]);
          acc[r][1] = fmaf(hv, wa.y, acc[r][1]);
          acc[r][2] = fmaf(hv, wa.z, acc[r][2]);
          acc[r][3] = fmaf(hv, wa.w, acc[r][3]);
          acc[r][4] = fmaf(hv, wb.x, acc[r][4]);
          acc[r][5] = fmaf(hv, wb.y, acc[r][5]);
          acc[r][6] = fmaf(hv, wb.z, acc[r][6]);
          acc[r][7] = fmaf(hv, wb.w, acc[r][7]);
        }
      }
    }
  }
#pragma unroll
  for (int r = 0; r < 5; ++r) {
    int t = r0 + r;
    float* dst = &part2[(size_t)(ks * TT + t) * 3072 + c0 + cq];
    *reinterpret_cast<float4*>(dst) = make_float4(acc[r][0], acc[r][1], acc[r][2], acc[r][3]);
    *reinterpret_cast<float4*>(dst + 4) = make_float4(acc[r][4], acc[r][5], acc[r][6], acc[r][7]);
  }
}

// ---------------- K6: final k-split reduce -> d_out ----------------
// grid 480, block 256  (40*3072 = 122880 outputs)
__global__ __launch_bounds__(256) void k6_final_reduce(
    const float* __restrict__ part2, float* __restrict__ out) {
  const int idx = blockIdx.x * 256 + threadIdx.x;
  float s = 0.f;
#pragma unroll
  for (int ks = 0; ks < 32; ++ks) s += part2[(size_t)ks * 122880 + idx];
  out[idx] = s;
}

extern "C" void kernel_launch(void* const* d_in, const int* in_sizes, int n_in,
                              void* d_out, int out_size, void* d_ws, size_t ws_size,
                              hipStream_t stream) {
  const float* hs       = (const float*)d_in[0];
  const float* Wq       = (const float*)d_in[1];
  const float* Wk       = (const float*)d_in[2];
  const float* Wv       = (const float*)d_in[3];
  const float* Wo       = (const float*)d_in[4];
  const float* k_cache  = (const float*)d_in[5];
  const float* v_cache  = (const float*)d_in[6];
  const float* inv_freq = (const float*)d_in[7];
  const int*   pos_ids  = (const int*)d_in[8];
  const int*   q_start  = (const int*)d_in[9];
  const int*   q_lens   = (const int*)d_in[10];
  const int*   kv_lens  = (const int*)d_in[11];
  const int*   blk_off  = (const int*)d_in[12];

  float* ws = (float*)d_ws;
  float* qbuf     = ws;                 // 40*4096
  float* kbuf     = ws + 163840;        // 40*2048
  float* vbuf     = ws + 245760;        // 40*2048
  float* attn_out = ws + 327680;        // 40*4096
  float* big      = ws + 491520;        // reused region
  float* part1    = big;                // 16*40*8192
  float* part_o   = big;                // 16384*256
  float* part_ml  = big + 4194304;      // 16384*2
  float* part2    = big;                // 32*40*3072
  float* out      = (float*)d_out;

  k1_qkv_gemm<<<512, 256, 0, stream>>>(hs, Wq, Wk, Wv, part1);
  k2_reduce_rope<<<1280, 256, 0, stream>>>(part1, inv_freq, pos_ids, qbuf, kbuf, vbuf);
  k3_attn_partial<<<2048, 256, 0, stream>>>(qbuf, kbuf, vbuf, k_cache, v_cache,
                                            blk_off, q_start, q_lens, kv_lens,
                                            part_o, part_ml);
  k4_attn_reduce<<<1024, 64, 0, stream>>>(part_o, part_ml, q_start, q_lens,
                                          kv_lens, attn_out);
  k5_out_gemm<<<384, 256, 0, stream>>>(attn_out, Wo, part2);
  k6_final_reduce<<<480, 256, 0, stream>>>(part2, out);
}